// Round 1
// baseline (1027.110 us; speedup 1.0000x reference)
//
#include <hip/hip_runtime.h>
#include <math.h>

#define BB 16
#define CC_ 512
#define NN 1024
#define HEADS 8
#define DD 64
#define O3 1536
#define EPSF 1e-5f
#define SCALEF 0.125f

__device__ __forceinline__ float4 ld4(const float* p){ return *reinterpret_cast<const float4*>(p); }
__device__ __forceinline__ void st4(float* p, float4 v){ *reinterpret_cast<float4*>(p) = v; }

// ---------------- GroupNorm stats: one block per (b, group) ----------------
__global__ __launch_bounds__(256,2) void gn_stats_k(const float* __restrict__ x,
                                                    float* __restrict__ stats){
  int blk = blockIdx.x;                       // b*8+g
  const float* p = x + (size_t)blk * (DD * NN);   // contiguous 65536 floats
  float s1 = 0.f, s2 = 0.f;
  const float4* p4 = reinterpret_cast<const float4*>(p);
  for(int i = threadIdx.x; i < 16384; i += 256){
    float4 v = p4[i];
    s1 += (v.x + v.y) + (v.z + v.w);
    s2 += v.x*v.x + v.y*v.y + v.z*v.z + v.w*v.w;
  }
  #pragma unroll
  for(int off = 32; off; off >>= 1){ s1 += __shfl_xor(s1, off); s2 += __shfl_xor(s2, off); }
  __shared__ float r1[4], r2[4];
  int tid = threadIdx.x;
  if((tid & 63) == 0){ r1[tid >> 6] = s1; r2[tid >> 6] = s2; }
  __syncthreads();
  if(tid == 0){
    float a  = r1[0] + r1[1] + r1[2] + r1[3];
    float b2 = r2[0] + r2[1] + r2[2] + r2[3];
    float mean = a * (1.f / 65536.f);
    float var  = b2 * (1.f / 65536.f) - mean * mean;
    stats[blk]       = mean;
    stats[128 + blk] = rsqrtf(var + EPSF);
  }
}

// ---------------- QKV GEMM with fused GroupNorm on the input ----------------
// out[b][o][n] = sum_c W[o][c] * (x[b][c][n]*s[b,c] + t[b,c]) + bias[o]
__global__ __launch_bounds__(256,4) void qkv_k(
    const float* __restrict__ x, const float* __restrict__ gnw, const float* __restrict__ gnb,
    const float* __restrict__ w, const float* __restrict__ bias,
    const float* __restrict__ stats, float* __restrict__ out){
  __shared__ float Wt[64][68];   // [c][o]
  __shared__ float Xt[64][68];   // [c][n]
  int n0 = blockIdx.x * 64, o0 = blockIdx.y * 64, b = blockIdx.z;
  int tid = threadIdx.x, ty = tid >> 4, tx = tid & 15;
  const float* xb = x + (size_t)b * CC_ * NN;
  float acc[4][4] = {};
  for(int c0 = 0; c0 < CC_; c0 += 64){
    __syncthreads();
    #pragma unroll
    for(int r = 0; r < 4; r++){
      int idx = tid + r * 256;
      int row = idx >> 4, q4 = idx & 15;
      // W tile, stored transposed
      float4 wv = ld4(w + (size_t)(o0 + row) * CC_ + c0 + q4 * 4);
      Wt[q4*4+0][row] = wv.x; Wt[q4*4+1][row] = wv.y;
      Wt[q4*4+2][row] = wv.z; Wt[q4*4+3][row] = wv.w;
      // X tile with GN folded in: row = channel
      int c = c0 + row, g = c >> 6;
      float mu = stats[b*8+g], rs = stats[128 + b*8+g];
      float s = rs * gnw[c];
      float t = gnb[c] - mu * s;
      float4 xv = ld4(xb + (size_t)c * NN + n0 + q4 * 4);
      st4(&Xt[row][q4*4], make_float4(xv.x*s+t, xv.y*s+t, xv.z*s+t, xv.w*s+t));
    }
    __syncthreads();
    #pragma unroll 8
    for(int kk = 0; kk < 64; kk++){
      float4 av = ld4(&Wt[kk][ty*4]);
      float4 bv = ld4(&Xt[kk][tx*4]);
      float aa[4] = {av.x, av.y, av.z, av.w};
      float bb[4] = {bv.x, bv.y, bv.z, bv.w};
      #pragma unroll
      for(int i = 0; i < 4; i++)
        #pragma unroll
        for(int j = 0; j < 4; j++)
          acc[i][j] += aa[i] * bb[j];
    }
  }
  #pragma unroll
  for(int i = 0; i < 4; i++){
    int o = o0 + ty*4 + i;
    float bo = bias[o];
    st4(out + (size_t)b * O3 * NN + (size_t)o * NN + n0 + tx*4,
        make_float4(acc[i][0]+bo, acc[i][1]+bo, acc[i][2]+bo, acc[i][3]+bo));
  }
}

// ---------------- Flash-style attention, one block per (b,h, 64 q-rows) ----------------
__global__ __launch_bounds__(256,3) void attn_k(const float* __restrict__ qkv,
                                                float* __restrict__ att){
  __shared__ float Qt[64][68];   // [c][n]
  __shared__ float KV[64][68];   // K phase: [c][m]; V phase: [m][c]
  __shared__ float Pt[64][68];   // [m][n]
  __shared__ float rfac[64];
  __shared__ float lrow[64];
  int bh = blockIdx.y, b = bh >> 3, h = bh & 7;
  int n0 = blockIdx.x * 64;
  int tid = threadIdx.x, ty = tid >> 4, tx = tid & 15;
  const float* qp = qkv + ((size_t)b * O3 + h * DD) * NN;
  const float* kp = qp + (size_t)CC_ * NN;
  const float* vp = qp + (size_t)2 * CC_ * NN;
  #pragma unroll
  for(int r = 0; r < 4; r++){
    int idx = tid + r * 256, row = idx >> 4, q4 = idx & 15;
    st4(&Qt[row][q4*4], ld4(qp + (size_t)row * NN + n0 + q4 * 4));
  }
  float m_run[4], l_run[4];
  #pragma unroll
  for(int i = 0; i < 4; i++){ m_run[i] = -INFINITY; l_run[i] = 0.f; }
  float acc[4][4] = {};
  for(int t = 0; t < 16; t++){
    int m0 = t * 64;
    __syncthreads();
    // stage K tile [c][m]
    #pragma unroll
    for(int r = 0; r < 4; r++){
      int idx = tid + r * 256, row = idx >> 4, q4 = idx & 15;
      st4(&KV[row][q4*4], ld4(kp + (size_t)row * NN + m0 + q4 * 4));
    }
    __syncthreads();
    // S = Q^T K  (s[i][j]: row n=4ty+i, col m=4tx+j)
    float s[4][4] = {};
    #pragma unroll 8
    for(int kk = 0; kk < 64; kk++){
      float4 qv = ld4(&Qt[kk][ty*4]);
      float4 kv = ld4(&KV[kk][tx*4]);
      float qa[4] = {qv.x, qv.y, qv.z, qv.w};
      float ka[4] = {kv.x, kv.y, kv.z, kv.w};
      #pragma unroll
      for(int i = 0; i < 4; i++)
        #pragma unroll
        for(int j = 0; j < 4; j++)
          s[i][j] += qa[i] * ka[j];
    }
    // online softmax over rows
    float p[4][4];
    #pragma unroll
    for(int i = 0; i < 4; i++){
      float mt = fmaxf(fmaxf(s[i][0], s[i][1]), fmaxf(s[i][2], s[i][3]));
      #pragma unroll
      for(int off = 1; off < 16; off <<= 1) mt = fmaxf(mt, __shfl_xor(mt, off));
      float mnew = fmaxf(m_run[i], mt * SCALEF);
      float r = __expf(m_run[i] - mnew);
      float lt = 0.f;
      #pragma unroll
      for(int j = 0; j < 4; j++){ p[i][j] = __expf(s[i][j] * SCALEF - mnew); lt += p[i][j]; }
      #pragma unroll
      for(int off = 1; off < 16; off <<= 1) lt += __shfl_xor(lt, off);
      l_run[i] = l_run[i] * r + lt;
      m_run[i] = mnew;
      if(tx == 0) rfac[ty*4 + i] = r;
    }
    // write P transposed: Pt[m][n]
    #pragma unroll
    for(int j = 0; j < 4; j++)
      #pragma unroll
      for(int i = 0; i < 4; i++)
        Pt[tx*4 + j][ty*4 + i] = p[i][j];
    __syncthreads();
    // stage V transposed: KV[m][c]
    #pragma unroll
    for(int r = 0; r < 4; r++){
      int idx = tid + r * 256, row = idx >> 4, q4 = idx & 15;  // row=c, q4=m-quad
      float4 vv = ld4(vp + (size_t)row * NN + m0 + q4 * 4);
      KV[q4*4+0][row] = vv.x; KV[q4*4+1][row] = vv.y;
      KV[q4*4+2][row] = vv.z; KV[q4*4+3][row] = vv.w;
    }
    __syncthreads();
    // rescale and accumulate PV: acc[i][j]: c=4ty+i, n=4tx+j
    float rj[4];
    #pragma unroll
    for(int j = 0; j < 4; j++) rj[j] = rfac[tx*4 + j];
    #pragma unroll
    for(int i = 0; i < 4; i++)
      #pragma unroll
      for(int j = 0; j < 4; j++) acc[i][j] *= rj[j];
    #pragma unroll 8
    for(int mm = 0; mm < 64; mm++){
      float4 vv = ld4(&KV[mm][ty*4]);
      float4 pv = ld4(&Pt[mm][tx*4]);
      float va[4] = {vv.x, vv.y, vv.z, vv.w};
      float pa[4] = {pv.x, pv.y, pv.z, pv.w};
      #pragma unroll
      for(int i = 0; i < 4; i++)
        #pragma unroll
        for(int j = 0; j < 4; j++)
          acc[i][j] += va[i] * pa[j];
    }
  }
  if(tx == 0){
    #pragma unroll
    for(int i = 0; i < 4; i++) lrow[ty*4 + i] = l_run[i];
  }
  __syncthreads();
  float linv[4];
  #pragma unroll
  for(int j = 0; j < 4; j++) linv[j] = 1.f / lrow[tx*4 + j];
  #pragma unroll
  for(int i = 0; i < 4; i++){
    int c = h * DD + ty*4 + i;
    st4(att + ((size_t)b * CC_ + c) * NN + n0 + tx*4,
        make_float4(acc[i][0]*linv[0], acc[i][1]*linv[1], acc[i][2]*linv[2], acc[i][3]*linv[3]));
  }
}

// ---------------- proj GEMM + bias + residual ----------------
__global__ __launch_bounds__(256,4) void proj_k(
    const float* __restrict__ att, const float* __restrict__ w, const float* __restrict__ bias,
    const float* __restrict__ resid, float* __restrict__ out){
  __shared__ float Wt[64][68];
  __shared__ float Xt[64][68];
  int n0 = blockIdx.x * 64, o0 = blockIdx.y * 64, b = blockIdx.z;
  int tid = threadIdx.x, ty = tid >> 4, tx = tid & 15;
  const float* ab = att + (size_t)b * CC_ * NN;
  float acc[4][4] = {};
  for(int c0 = 0; c0 < CC_; c0 += 64){
    __syncthreads();
    #pragma unroll
    for(int r = 0; r < 4; r++){
      int idx = tid + r * 256;
      int row = idx >> 4, q4 = idx & 15;
      float4 wv = ld4(w + (size_t)(o0 + row) * CC_ + c0 + q4 * 4);
      Wt[q4*4+0][row] = wv.x; Wt[q4*4+1][row] = wv.y;
      Wt[q4*4+2][row] = wv.z; Wt[q4*4+3][row] = wv.w;
      st4(&Xt[row][q4*4], ld4(ab + (size_t)(c0 + row) * NN + n0 + q4 * 4));
    }
    __syncthreads();
    #pragma unroll 8
    for(int kk = 0; kk < 64; kk++){
      float4 av = ld4(&Wt[kk][ty*4]);
      float4 bv = ld4(&Xt[kk][tx*4]);
      float aa[4] = {av.x, av.y, av.z, av.w};
      float bb[4] = {bv.x, bv.y, bv.z, bv.w};
      #pragma unroll
      for(int i = 0; i < 4; i++)
        #pragma unroll
        for(int j = 0; j < 4; j++)
          acc[i][j] += aa[i] * bb[j];
    }
  }
  #pragma unroll
  for(int i = 0; i < 4; i++){
    int o = o0 + ty*4 + i;
    float bo = bias[o];
    size_t off = (size_t)b * CC_ * NN + (size_t)o * NN + n0 + tx*4;
    float4 rv = ld4(resid + off);
    st4(out + off, make_float4(acc[i][0]+bo+rv.x, acc[i][1]+bo+rv.y,
                               acc[i][2]+bo+rv.z, acc[i][3]+bo+rv.w));
  }
}

extern "C" void kernel_launch(void* const* d_in, const int* in_sizes, int n_in,
                              void* d_out, int out_size, void* d_ws, size_t ws_size,
                              hipStream_t stream){
  const float* x     = (const float*)d_in[0];
  const float* gnw   = (const float*)d_in[1];
  const float* gnb   = (const float*)d_in[2];
  const float* qkvw  = (const float*)d_in[3];
  const float* qkvb  = (const float*)d_in[4];
  const float* projw = (const float*)d_in[5];
  const float* projb = (const float*)d_in[6];
  float* out = (float*)d_out;
  float* ws  = (float*)d_ws;
  float* qkv   = ws;                               // 16*1536*1024 = 25165824 floats
  float* att   = ws + 25165824;                    // 16*512*1024  =  8388608 floats
  float* stats = ws + 25165824 + 8388608;          // 256 floats (mean | rstd)

  hipLaunchKernelGGL(gn_stats_k, dim3(128), dim3(256), 0, stream, x, stats);
  hipLaunchKernelGGL(qkv_k,  dim3(16, 24, 16), dim3(256), 0, stream,
                     x, gnw, gnb, qkvw, qkvb, stats, qkv);
  hipLaunchKernelGGL(attn_k, dim3(16, 128),    dim3(256), 0, stream, qkv, att);
  hipLaunchKernelGGL(proj_k, dim3(16, 8, 16),  dim3(256), 0, stream,
                     att, projw, projb, x, out);
}

// Round 4
// 201.472 us; speedup vs baseline: 5.0980x; 5.0980x over previous
//
#include <hip/hip_runtime.h>
#include <math.h>

typedef short bf16x8 __attribute__((ext_vector_type(8)));
typedef float f32x4  __attribute__((ext_vector_type(4)));
#define MFMA16(a,b,c) __builtin_amdgcn_mfma_f32_16x16x32_bf16(a,b,c,0,0,0)

#define EPSF 1e-5f
#define SCALEF 0.125f

__device__ __forceinline__ unsigned int bfr(float f){      // f32 -> bf16 bits, RNE
  unsigned int u = __float_as_uint(f);
  return (u + 0x7fffu + ((u >> 16) & 1u)) >> 16;
}
__device__ __forceinline__ unsigned int pk2(float a, float b){
  return bfr(a) | (bfr(b) << 16);
}

// ---------------- GroupNorm stats: one block per (b, group) ----------------
__global__ __launch_bounds__(256,2) void gn_stats_k(const float* __restrict__ x,
                                                    float* __restrict__ stats){
  int blk = blockIdx.x;                       // b*8+g
  const float4* p4 = reinterpret_cast<const float4*>(x + (size_t)blk * 65536);
  float s1 = 0.f, s2 = 0.f;
  for(int i = threadIdx.x; i < 16384; i += 256){
    float4 v = p4[i];
    s1 += (v.x + v.y) + (v.z + v.w);
    s2 += v.x*v.x + v.y*v.y + v.z*v.z + v.w*v.w;
  }
  #pragma unroll
  for(int off = 32; off; off >>= 1){ s1 += __shfl_xor(s1, off); s2 += __shfl_xor(s2, off); }
  __shared__ float r1[4], r2[4];
  int tid = threadIdx.x;
  if((tid & 63) == 0){ r1[tid >> 6] = s1; r2[tid >> 6] = s2; }
  __syncthreads();
  if(tid == 0){
    float a  = r1[0] + r1[1] + r1[2] + r1[3];
    float b2 = r2[0] + r2[1] + r2[2] + r2[3];
    float mean = a * (1.f / 65536.f);
    float var  = b2 * (1.f / 65536.f) - mean * mean;
    stats[blk]       = mean;
    stats[128 + blk] = rsqrtf(var + EPSF);
  }
}

// ---------------- weight f32 -> bf16 ----------------
__global__ __launch_bounds__(256) void wcvt_k(const float* __restrict__ src,
                                              unsigned int* __restrict__ dst){
  int i = blockIdx.x * 256 + threadIdx.x;            // one float4 -> uint2
  float4 v = reinterpret_cast<const float4*>(src)[i];
  uint2 r; r.x = pk2(v.x, v.y); r.y = pk2(v.z, v.w);
  reinterpret_cast<uint2*>(dst)[i] = r;
}

// ---------------- GN-apply + transpose: xnT[b][n][c] bf16 ----------------
__global__ __launch_bounds__(256) void gnT_k(const float* __restrict__ x,
                                             const float* __restrict__ gnw,
                                             const float* __restrict__ gnb,
                                             const float* __restrict__ stats,
                                             unsigned short* __restrict__ xnT){
  __shared__ float Xl[64 * 65];
  int b = blockIdx.z, c0 = blockIdx.y * 64, n0 = blockIdx.x * 64, tid = threadIdx.x;
  int nq = tid & 15, rr = tid >> 4;
  #pragma unroll
  for(int p = 0; p < 4; p++){
    int cl = p * 16 + rr, c = c0 + cl, gi = c >> 6;
    float mu = stats[b*8 + gi], rs = stats[128 + b*8 + gi];
    float s = rs * gnw[c], t = gnb[c] - mu * s;
    float4 v = *reinterpret_cast<const float4*>(x + ((size_t)(b*512 + c))*1024 + n0 + 4*nq);
    Xl[(4*nq+0)*65 + cl] = v.x*s + t;
    Xl[(4*nq+1)*65 + cl] = v.y*s + t;
    Xl[(4*nq+2)*65 + cl] = v.z*s + t;
    Xl[(4*nq+3)*65 + cl] = v.w*s + t;
  }
  __syncthreads();
  int n = tid >> 2, cq = tid & 3;                    // 16 cols per thread
  float f[16];
  #pragma unroll
  for(int k = 0; k < 16; k++) f[k] = Xl[n*65 + 16*cq + k];
  uint4 w0, w1;
  w0.x = pk2(f[0],f[1]);  w0.y = pk2(f[2],f[3]);  w0.z = pk2(f[4],f[5]);  w0.w = pk2(f[6],f[7]);
  w1.x = pk2(f[8],f[9]);  w1.y = pk2(f[10],f[11]);w1.z = pk2(f[12],f[13]);w1.w = pk2(f[14],f[15]);
  unsigned short* dp = xnT + ((size_t)(b*1024 + n0 + n))*512 + c0 + 16*cq;
  *reinterpret_cast<uint4*>(dp)     = w0;
  *reinterpret_cast<uint4*>(dp + 8) = w1;
}

// ---------------- QKV GEMM bf16 MFMA: writes Q,K transposed + V natural ----------------
__global__ __launch_bounds__(256) void qkv_mm(const unsigned short* __restrict__ A,
                                              const unsigned short* __restrict__ Bx,
                                              const float* __restrict__ bias,
                                              unsigned short* __restrict__ T,
                                              unsigned short* __restrict__ V){
  __shared__ __align__(16) unsigned short As[128*40], Bs[128*40];
  int tid = threadIdx.x;
  int n0 = blockIdx.x*128, o0 = blockIdx.y*128, b = blockIdx.z;
  int wid = tid >> 6, wr = wid >> 1, wc = wid & 1, ln = tid & 15, g = (tid >> 4) & 3;
  int row = tid >> 1, hf = tid & 1;
  const unsigned short* Ag = A + (size_t)(o0 + row)*512 + hf*16;
  const unsigned short* Bg = Bx + ((size_t)(b*1024 + n0 + row))*512 + hf*16;
  f32x4 acc[4][4] = {};
  for(int k0 = 0; k0 < 512; k0 += 32){
    __syncthreads();
    *reinterpret_cast<bf16x8*>(&As[row*40 + hf*16])     = *reinterpret_cast<const bf16x8*>(Ag + k0);
    *reinterpret_cast<bf16x8*>(&As[row*40 + hf*16 + 8]) = *reinterpret_cast<const bf16x8*>(Ag + k0 + 8);
    *reinterpret_cast<bf16x8*>(&Bs[row*40 + hf*16])     = *reinterpret_cast<const bf16x8*>(Bg + k0);
    *reinterpret_cast<bf16x8*>(&Bs[row*40 + hf*16 + 8]) = *reinterpret_cast<const bf16x8*>(Bg + k0 + 8);
    __syncthreads();
    bf16x8 af[4], bfv[4];
    #pragma unroll
    for(int mf = 0; mf < 4; mf++)
      af[mf] = *reinterpret_cast<const bf16x8*>(&As[(wr*64 + 16*mf + ln)*40 + 8*g]);
    #pragma unroll
    for(int nf = 0; nf < 4; nf++)
      bfv[nf] = *reinterpret_cast<const bf16x8*>(&Bs[(wc*64 + 16*nf + ln)*40 + 8*g]);
    #pragma unroll
    for(int mf = 0; mf < 4; mf++)
      #pragma unroll
      for(int nf = 0; nf < 4; nf++)
        acc[mf][nf] = MFMA16(af[mf], bfv[nf], acc[mf][nf]);
  }
  int obase = o0 + wr*64, nbase = n0 + wc*64;
  if(obase < 1024){                                   // Q or K rows -> transposed store
    #pragma unroll
    for(int mf = 0; mf < 4; mf++)
      #pragma unroll
      for(int r = 0; r < 4; r++){
        int o = obase + 16*mf + 4*g + r;  float bo = bias[o];
        #pragma unroll
        for(int nf = 0; nf < 4; nf++){
          int n = nbase + 16*nf + ln;
          T[((size_t)(b*1024 + n))*1024 + o] = (unsigned short)bfr(acc[mf][nf][r] + bo);
        }
      }
  } else {                                            // V rows -> natural store
    #pragma unroll
    for(int mf = 0; mf < 4; mf++)
      #pragma unroll
      for(int r = 0; r < 4; r++){
        int o = obase + 16*mf + 4*g + r;  float bo = bias[o];
        #pragma unroll
        for(int nf = 0; nf < 4; nf++){
          int n = nbase + 16*nf + ln;
          V[((size_t)(b*512 + o - 1024))*1024 + n] = (unsigned short)bfr(acc[mf][nf][r] + bo);
        }
      }
  }
}

// ---------------- Flash attention, bf16 MFMA, swapped-QK^T ----------------
__global__ __launch_bounds__(256) void attn_bf_k(const unsigned short* __restrict__ T,
                                                 const unsigned short* __restrict__ V,
                                                 float* __restrict__ attT){
  __shared__ __align__(16) unsigned short KT[64*72];
  __shared__ __align__(16) unsigned short Vt[64*72];
  __shared__ __align__(16) unsigned int   Pl[4*16*36];
  int tid = threadIdx.x;
  int bh = blockIdx.y, b = bh >> 3, h = bh & 7;
  int n0 = blockIdx.x * 64;
  int wq = tid >> 6, ln = tid & 15, g = (tid >> 4) & 3;
  int nl = n0 + wq*16 + ln;                 // this lane's q-row
  const unsigned short* Tb = T + ((size_t)b << 20);
  bf16x8 qf0 = *reinterpret_cast<const bf16x8*>(Tb + (size_t)nl*1024 + h*64 + 8*g);
  bf16x8 qf1 = *reinterpret_cast<const bf16x8*>(Tb + (size_t)nl*1024 + h*64 + 32 + 8*g);
  f32x4 acc[4] = {};
  float m_run = -INFINITY, l_run = 0.f;
  int srow = tid >> 2, sq = tid & 3;
  const unsigned short* kg = Tb + 512 + h*64;
  const unsigned short* vg = V + ((size_t)(b*512 + h*64))*1024;
  int pbase = wq*576 + ln*36;
  for(int t = 0; t < 16; t++){
    int m0 = t * 64;
    __syncthreads();
    // stage K tile [m][c] — FULL 64x64 coverage: 16 shorts per thread (r4 fix)
    *reinterpret_cast<bf16x8*>(&KT[srow*72 + 16*sq]) =
        *reinterpret_cast<const bf16x8*>(kg + (size_t)(m0 + srow)*1024 + 16*sq);
    *reinterpret_cast<bf16x8*>(&KT[srow*72 + 16*sq + 8]) =
        *reinterpret_cast<const bf16x8*>(kg + (size_t)(m0 + srow)*1024 + 16*sq + 8);
    // stage V tile [c][m]
    *reinterpret_cast<bf16x8*>(&Vt[srow*72 + 16*sq]) =
        *reinterpret_cast<const bf16x8*>(vg + (size_t)srow*1024 + m0 + 16*sq);
    *reinterpret_cast<bf16x8*>(&Vt[srow*72 + 16*sq + 8]) =
        *reinterpret_cast<const bf16x8*>(vg + (size_t)srow*1024 + m0 + 16*sq + 8);
    __syncthreads();
    f32x4 sf[4];
    #pragma unroll
    for(int mf = 0; mf < 4; mf++){
      bf16x8 a0 = *reinterpret_cast<const bf16x8*>(&KT[(16*mf + ln)*72 + 8*g]);
      bf16x8 a1 = *reinterpret_cast<const bf16x8*>(&KT[(16*mf + ln)*72 + 32 + 8*g]);
      f32x4 z = {0.f, 0.f, 0.f, 0.f};
      z = MFMA16(a0, qf0, z);
      sf[mf] = MFMA16(a1, qf1, z);
    }
    float p[16];
    float pm = -INFINITY;
    #pragma unroll
    for(int mf = 0; mf < 4; mf++)
      #pragma unroll
      for(int r = 0; r < 4; r++){
        float v = sf[mf][r] * SCALEF;
        p[mf*4 + r] = v;
        pm = fmaxf(pm, v);
      }
    pm = fmaxf(pm, __shfl_xor(pm, 16));
    pm = fmaxf(pm, __shfl_xor(pm, 32));
    float mnew = fmaxf(m_run, pm);
    float rf = __expf(m_run - mnew);
    float ls = 0.f;
    #pragma unroll
    for(int i = 0; i < 16; i++){ p[i] = __expf(p[i] - mnew); ls += p[i]; }
    ls += __shfl_xor(ls, 16);
    ls += __shfl_xor(ls, 32);
    l_run = l_run * rf + ls;
    m_run = mnew;
    #pragma unroll
    for(int cf = 0; cf < 4; cf++) acc[cf] *= rf;
    // pack P (bf16 pairs) into per-wave LDS, re-read as B-frags (k-contig 8)
    #pragma unroll
    for(int mt = 0; mt < 4; mt++){
      Pl[pbase + 8*mt + 2*g + 0] = pk2(p[4*mt + 0], p[4*mt + 1]);
      Pl[pbase + 8*mt + 2*g + 1] = pk2(p[4*mt + 2], p[4*mt + 3]);
    }
    __syncthreads();   // order Pl stores before the uint4 fragment loads
    union { uint4 u; bf16x8 hv; } pb0, pb1;
    pb0.u = *reinterpret_cast<const uint4*>(&Pl[pbase + 4*g]);
    pb1.u = *reinterpret_cast<const uint4*>(&Pl[pbase + 16 + 4*g]);
    #pragma unroll
    for(int cf = 0; cf < 4; cf++){
      bf16x8 v0 = *reinterpret_cast<const bf16x8*>(&Vt[(16*cf + ln)*72 + 8*g]);
      bf16x8 v1 = *reinterpret_cast<const bf16x8*>(&Vt[(16*cf + ln)*72 + 32 + 8*g]);
      acc[cf] = MFMA16(v0, pb0.hv, acc[cf]);
      acc[cf] = MFMA16(v1, pb1.hv, acc[cf]);
    }
  }
  float inv = 1.f / l_run;
  float* op = attT + ((size_t)(b*1024 + nl))*512 + h*64;
  #pragma unroll
  for(int cf = 0; cf < 4; cf++)
    #pragma unroll
    for(int r = 0; r < 4; r++)
      op[16*cf + 4*g + r] = acc[cf][r] * inv;
}

// ---------------- proj GEMM bf16 MFMA + bias + residual ----------------
__global__ __launch_bounds__(256) void proj_mm(const unsigned short* __restrict__ A,
                                               const float* __restrict__ Bf,
                                               const float* __restrict__ bias,
                                               const float* __restrict__ resid,
                                               float* __restrict__ out){
  __shared__ __align__(16) unsigned short As[128*40], Bs[128*40];
  int tid = threadIdx.x;
  int n0 = blockIdx.x*128, o0 = blockIdx.y*128, b = blockIdx.z;
  int wid = tid >> 6, wr = wid >> 1, wc = wid & 1, ln = tid & 15, g = (tid >> 4) & 3;
  int row = tid >> 1, hf = tid & 1;
  const unsigned short* Ag = A + (size_t)(o0 + row)*512 + hf*16;
  const float* Bg = Bf + ((size_t)(b*1024 + n0 + row))*512 + hf*16;
  f32x4 acc[4][4] = {};
  for(int k0 = 0; k0 < 512; k0 += 32){
    __syncthreads();
    *reinterpret_cast<bf16x8*>(&As[row*40 + hf*16])     = *reinterpret_cast<const bf16x8*>(Ag + k0);
    *reinterpret_cast<bf16x8*>(&As[row*40 + hf*16 + 8]) = *reinterpret_cast<const bf16x8*>(Ag + k0 + 8);
    float4 v0 = *reinterpret_cast<const float4*>(Bg + k0);
    float4 v1 = *reinterpret_cast<const float4*>(Bg + k0 + 4);
    float4 v2 = *reinterpret_cast<const float4*>(Bg + k0 + 8);
    float4 v3 = *reinterpret_cast<const float4*>(Bg + k0 + 12);
    uint4 w0, w1;
    w0.x = pk2(v0.x,v0.y); w0.y = pk2(v0.z,v0.w); w0.z = pk2(v1.x,v1.y); w0.w = pk2(v1.z,v1.w);
    w1.x = pk2(v2.x,v2.y); w1.y = pk2(v2.z,v2.w); w1.z = pk2(v3.x,v3.y); w1.w = pk2(v3.z,v3.w);
    *reinterpret_cast<uint4*>(&Bs[row*40 + hf*16])     = w0;
    *reinterpret_cast<uint4*>(&Bs[row*40 + hf*16 + 8]) = w1;
    __syncthreads();
    bf16x8 af[4], bfv[4];
    #pragma unroll
    for(int mf = 0; mf < 4; mf++)
      af[mf] = *reinterpret_cast<const bf16x8*>(&As[(wr*64 + 16*mf + ln)*40 + 8*g]);
    #pragma unroll
    for(int nf = 0; nf < 4; nf++)
      bfv[nf] = *reinterpret_cast<const bf16x8*>(&Bs[(wc*64 + 16*nf + ln)*40 + 8*g]);
    #pragma unroll
    for(int mf = 0; mf < 4; mf++)
      #pragma unroll
      for(int nf = 0; nf < 4; nf++)
        acc[mf][nf] = MFMA16(af[mf], bfv[nf], acc[mf][nf]);
  }
  #pragma unroll
  for(int mf = 0; mf < 4; mf++)
    #pragma unroll
    for(int r = 0; r < 4; r++){
      int o = o0 + wr*64 + 16*mf + 4*g + r;
      float bo = bias[o];
      #pragma unroll
      for(int nf = 0; nf < 4; nf++){
        int n = n0 + wc*64 + 16*nf + ln;
        size_t off = ((size_t)(b*512 + o))*1024 + n;
        out[off] = acc[mf][nf][r] + bo + resid[off];
      }
    }
}

extern "C" void kernel_launch(void* const* d_in, const int* in_sizes, int n_in,
                              void* d_out, int out_size, void* d_ws, size_t ws_size,
                              hipStream_t stream){
  const float* x     = (const float*)d_in[0];
  const float* gnw   = (const float*)d_in[1];
  const float* gnb   = (const float*)d_in[2];
  const float* qkvw  = (const float*)d_in[3];
  const float* qkvb  = (const float*)d_in[4];
  const float* projw = (const float*)d_in[5];
  const float* projb = (const float*)d_in[6];
  float* out = (float*)d_out;

  char* w = (char*)d_ws;
  float* stats = (float*)w;            w += 1024;
  unsigned short* wqb = (unsigned short*)w;  w += (size_t)1536*512*2;
  unsigned short* wpb = (unsigned short*)w;  w += (size_t)512*512*2;
  unsigned short* xnT = (unsigned short*)w;  w += (size_t)16*1024*512*2;
  unsigned short* Tqk = (unsigned short*)w;  w += (size_t)16*1024*1024*2;
  unsigned short* Vb  = (unsigned short*)w;  w += (size_t)16*512*1024*2;
  float* attT = (float*)w;             w += (size_t)16*1024*512*4;

  hipLaunchKernelGGL(gn_stats_k, dim3(128), dim3(256), 0, stream, x, stats);
  hipLaunchKernelGGL(wcvt_k, dim3(768), dim3(256), 0, stream, qkvw, (unsigned int*)wqb);
  hipLaunchKernelGGL(wcvt_k, dim3(256), dim3(256), 0, stream, projw, (unsigned int*)wpb);
  hipLaunchKernelGGL(gnT_k, dim3(16, 8, 16), dim3(256), 0, stream, x, gnw, gnb, stats, xnT);
  hipLaunchKernelGGL(qkv_mm, dim3(8, 12, 16), dim3(256), 0, stream, wqb, xnT, qkvb, Tqk, Vb);
  hipLaunchKernelGGL(attn_bf_k, dim3(16, 128), dim3(256), 0, stream, Tqk, Vb, attT);
  hipLaunchKernelGGL(proj_mm, dim3(8, 4, 16), dim3(256), 0, stream, wpb, attT, projb, x, out);
}